// Round 7
// baseline (4204.897 us; speedup 1.0000x reference)
//
#include <hip/hip_runtime.h>

// ---------------- problem constants ----------------
#define HND    233
#define NL     6
#define GPL    15             // WGs per layer
#define UPW    16             // units per WG (15*16 = 240 >= 233)
#define ROWS   64             // gate rows per WG
#define TSTEPS 16
#define FSTEPS 96
#define NSLOT  (TSTEPS*FSTEPS)
#define CDIM   12
#define G4H    (4*HND)        // 932
#define HP     240            // preferred hout row stride (floats)
#define VINW   496            // vin stream buffer: [x 240 | h 240 | pad 16]
#define NTICK  (6*95+15+1)    // 586 wavefront ticks
#define NHEAD  3
#define BLOCK  256
#define NWORD  234            // u64 words per stream (117 x + 117 h)
#define AG     __HIP_MEMORY_SCOPE_AGENT
#define SENT   0x7FBADBADu    // NaN pattern: unreachable by real data (backstop)

typedef unsigned long long u64;

__device__ __forceinline__ float sigf(float x) { return 1.f / (1.f + expf(-x)); }
__device__ __forceinline__ bool rdy(u64 v) {
  return ((unsigned)v != SENT) && ((unsigned)(v >> 32) != SENT);
}

// Re-poison hout (backstop sentinel) and zero per-slot publish counters.
__global__ void init_kernel(unsigned* __restrict__ hout, int* __restrict__ cnt, int hp) {
  size_t i = (size_t)blockIdx.x * blockDim.x + threadIdx.x;
  size_t stride = (size_t)gridDim.x * blockDim.x;
  const size_t nh = (size_t)NL * NSLOT * hp;
  for (size_t k = i; k < nh; k += stride) hout[k] = ((int)(k % hp) < HND) ? SENT : 0u;
  for (size_t k = i; k < (size_t)NL * NSLOT; k += stride) cnt[k] = 0;
}

// grid: NL*GPL layer WGs + NHEAD head WGs, 256 threads each.
// Wavefront: layer l processes slot (f,t) at its loop tick m = 6f+t; <=3
// concurrent f-streams. Exchange protocol: producers store data (MALL-direct
// relaxed atomics), s_waitcnt vmcnt(0), then atomicAdd cnt[l][slot]; consumers
// spin on the counter (==GPL) then bulk-load once (SENT re-poll as backstop).
__global__ void __launch_bounds__(BLOCK, 1) lstm_pipe(
    const float* __restrict__ X,
    const float* __restrict__ Wih0, const float* __restrict__ Wih,
    const float* __restrict__ Whh,  const float* __restrict__ bih,
    const float* __restrict__ bhh,  const float* __restrict__ Wl,
    const float* __restrict__ bl,   float* __restrict__ out,
    float* __restrict__ hout, int* __restrict__ cnt, int hps) {
  __shared__ float vin[3][VINW];        // per-stream [x|h|pad], k-indexed
  __shared__ float part[3][BLOCK];
  __shared__ float bias[ROWS];
  __shared__ float cst[3][UPW];         // c-state, keyed by f%3
  __shared__ float wih0s[ROWS][CDIM];   // l0: raw Wih0 rows (f==0 correction)
  __shared__ float xs[TSTEPS][CDIM];    // l0: f==0 seed = X[t][95][:]
  __shared__ float wlh[CDIM][HP];       // Wl padded (l0 fold + head dot)

  const int tid = threadIdx.x;
  const int bid = blockIdx.x;
  u64* hu = (u64*)hout;

  if (bid >= NL * GPL) {
    // ---------------- head WGs: out[t][f][:] = Wl.h5(f,t)+bl, f%3==hid ----
    const int hid = bid - NL * GPL;
    for (int i = tid; i < CDIM * HP; i += BLOCK) {
      int rr = i / HP, k = i % HP;
      ((float*)wlh)[i] = (k < HND) ? Wl[rr * HND + k] : 0.f;
    }
    for (int i = tid; i < VINW; i += BLOCK) vin[0][i] = 0.f;
    __syncthreads();
    for (int f = hid; f < FSTEPS; f += NHEAD) {
      for (int t = 0; t < TSTEPS; ++t) {
        const int slot = 16 * f + t;
        {   // counter spin (uniform; same-address loads coalesce per wave)
          const int* cp = cnt + 5 * NSLOT + slot;
          long gd = 0;
          while (__hip_atomic_load(cp, __ATOMIC_RELAXED, AG) < GPL) {
            if (++gd > (1L << 20)) break;
            if (gd > 2) __builtin_amdgcn_s_sleep(1);
          }
        }
        if (tid < 117) {
          const u64* src = hu + ((size_t)5 * NSLOT + slot) * hps + tid;
          u64 v; long gd = 0;
          for (;;) {          // backstop: exits first pass when counter honest
            v = __hip_atomic_load(src, __ATOMIC_RELAXED, AG);
            if (rdy(v)) break;
            if (++gd > (1L << 20)) break;
            if (gd > 2) __builtin_amdgcn_s_sleep(1);
          }
          *(u64*)&vin[0][2 * tid] = v;
        }
        __syncthreads();
        if (tid < 48) {
          int rr = tid >> 2, q = tid & 3;
          const float4* wr = (const float4*)&wlh[rr][0];
          const float4* hv = (const float4*)&vin[0][0];
          float a = 0.f;
          #pragma unroll
          for (int c = 0; c < 15; ++c) {
            float4 x0 = wr[q * 15 + c], y0 = hv[q * 15 + c];
            a = fmaf(x0.w, y0.w, fmaf(x0.z, y0.z, fmaf(x0.y, y0.y, fmaf(x0.x, y0.x, a))));
          }
          a += __shfl_xor(a, 1);
          a += __shfl_xor(a, 2);
          if (q == 0) out[((size_t)t * FSTEPS + f) * CDIM + rr] = a + bl[rr];
        }
        __syncthreads();
      }
    }
    return;
  }

  // ---------------- layer workgroup ----------------
  const int l = bid / GPL, g = bid % GPL;
  const int j0 = g * UPW;
  const int U = min(UPW, HND - j0);            // last WG: 9 units
  const int r = tid & 63, q = tid >> 6;        // matvec row / k-quarter
  const int u = r >> 2, gt = r & 3;
  const int grow = gt * HND + j0 + u;
  const bool rowok = (u < U);

  // ---- small LDS tables
  if (l == 0) {
    for (int i = tid; i < CDIM * HP; i += BLOCK) {
      int rr = i / HP, k = i % HP;
      ((float*)wlh)[i] = (k < HND) ? Wl[rr * HND + k] : 0.f;
    }
    for (int i = tid; i < ROWS * CDIM; i += BLOCK) {
      int rr = i / CDIM, c = i % CDIM;
      int uu = rr >> 2, g2 = rr & 3;
      wih0s[rr][c] = (uu < U) ? Wih0[(g2 * HND + j0 + uu) * CDIM + c] : 0.f;
    }
    for (int i = tid; i < TSTEPS * CDIM; i += BLOCK)
      xs[i / CDIM][i % CDIM] = X[((size_t)(i / CDIM) * 96 + 95) * CDIM + (i % CDIM)];
  }
  for (int i = tid; i < 3 * VINW; i += BLOCK) ((float*)vin)[i] = 0.f;
  __syncthreads();

  // ---- weights into REGISTERS (121-float slice; statically indexed)
  // row layout: [x-weights 240 | Whh 240 | pad 16]; l0 x-weights = Wih0 @ Wl.
  float4 w4[31];
  const float* wihl = Wih + (size_t)(l - 1) * G4H * HND;
  const float* whhl = Whh + (size_t)l * G4H * HND;
  #pragma unroll
  for (int j = 0; j < 31; ++j) {
    float e[4];
    #pragma unroll
    for (int ee = 0; ee < 4; ++ee) {
      const int idx = (q * 31 + j) * 4 + ee;
      float v = 0.f;
      if (rowok) {
        if (idx < HND) {
          if (l == 0) {
            float acc = 0.f;
            #pragma unroll
            for (int c = 0; c < CDIM; ++c) acc = fmaf(wih0s[r][c], wlh[c][idx], acc);
            v = acc;
          } else {
            v = wihl[(size_t)grow * HND + idx];
          }
        } else if (idx >= HP && idx < HP + HND) {
          v = whhl[(size_t)grow * HND + (idx - HP)];
        }
      }
      e[ee] = v;
    }
    w4[j] = make_float4(e[0], e[1], e[2], e[3]);
  }
  if (tid < ROWS) {
    float b = 0.f;
    if (rowok) {
      b = bih[l * G4H + grow] + bhh[l * G4H + grow];
      if (l == 0) {   // fold Wih0 @ bl into the bias
        #pragma unroll
        for (int c = 0; c < CDIM; ++c) b = fmaf(wih0s[tid][c], bl[c], b);
      }
    }
    bias[tid] = b;
  }
  __syncthreads();

  // ---- wavefront tick loop: m = 6f + t
  for (int m = 0; m < NTICK; ++m) {
    const int fh0 = m / 6;
    const int f_hi = (fh0 > 95) ? 95 : fh0;
    const int f_lo = (m < 10) ? 0 : (m - 10) / 6;
    const int nk = f_hi - f_lo + 1;              // active streams (1..3)

    // ---- counter spin: up to 6 gates (3 streams x {x,h}), uniform
    {
      const int* cw[6] = {nullptr, nullptr, nullptr, nullptr, nullptr, nullptr};
      #pragma unroll
      for (int k = 0; k < 3; ++k) {
        const int f = f_lo + k;
        if (f <= f_hi) {
          const int t = m - 6 * f;
          if (l == 0) {
            if (f > 0) cw[2 * k] = cnt + 5 * NSLOT + 16 * (f - 1) + t;
          } else {
            cw[2 * k] = cnt + (l - 1) * NSLOT + 16 * f + t;
          }
          if (t > 0) cw[2 * k + 1] = cnt + l * NSLOT + 16 * f + (t - 1);
        }
      }
      long gd = 0;
      for (;;) {
        bool miss = false;
        #pragma unroll
        for (int i = 0; i < 6; ++i) {
          if (cw[i]) {
            if (__hip_atomic_load(cw[i], __ATOMIC_RELAXED, AG) >= GPL) cw[i] = nullptr;
            else miss = true;
          }
        }
        if (!miss) break;
        if (++gd > (1L << 20)) break;            // bail loudly, no hang
        if (gd > 2) __builtin_amdgcn_s_sleep(1);
      }
    }

    // ---- bulk data load (one volley; SENT re-poll is a backstop only)
    const u64 *s0 = nullptr, *s1 = nullptr, *s2 = nullptr;
    u64 *d0 = nullptr, *d1 = nullptr, *d2 = nullptr;

    auto setup = [&](int w, const u64*& sp, u64*& dp) {
      const int k = w / NWORD;
      const int f = f_lo + k;
      if (f > f_hi) return;
      const int t = m - 6 * f;
      const int o = w - k * NWORD;
      if (o < 117) {                       // x-section word
        if (l == 0 && f == 0) {            // seed from X (12 floats, rest 0)
          vin[k][2 * o]     = (2 * o     < CDIM) ? xs[t][2 * o]     : 0.f;
          vin[k][2 * o + 1] = (2 * o + 1 < CDIM) ? xs[t][2 * o + 1] : 0.f;
          return;
        }
        sp = (l == 0)
           ? hu + ((size_t)5 * NSLOT + 16 * (f - 1) + t) * hps + o
           : hu + ((size_t)(l - 1) * NSLOT + 16 * f + t) * hps + o;
        dp = (u64*)&vin[k][2 * o];
      } else {                             // h-section word
        const int jj = o - 117;
        if (t == 0) {
          vin[k][HP + 2 * jj] = 0.f; vin[k][HP + 2 * jj + 1] = 0.f;
          return;
        }
        sp = hu + ((size_t)l * NSLOT + 16 * f + t - 1) * hps + jj;
        dp = (u64*)&vin[k][HP + 2 * jj];
      }
    };
    setup(tid, s0, d0);
    setup(tid + 256, s1, d1);
    if (tid + 512 < 3 * NWORD) setup(tid + 512, s2, d2);

    long gd = 0;
    while (s0 || s1 || s2) {
      if (s0) { u64 v = __hip_atomic_load(s0, __ATOMIC_RELAXED, AG); if (rdy(v)) { *d0 = v; s0 = nullptr; } }
      if (s1) { u64 v = __hip_atomic_load(s1, __ATOMIC_RELAXED, AG); if (rdy(v)) { *d1 = v; s1 = nullptr; } }
      if (s2) { u64 v = __hip_atomic_load(s2, __ATOMIC_RELAXED, AG); if (rdy(v)) { *d2 = v; s2 = nullptr; } }
      if (++gd > (1L << 20)) break;
      if (gd > 4) __builtin_amdgcn_s_sleep(1);
    }
    __syncthreads();

    // ---- matvec: active streams only; weights in regs, vin broadcast reads
    const float4* va = (const float4*)&vin[0][0];
    const float4* vb = (const float4*)&vin[1][0];
    const float4* vc = (const float4*)&vin[2][0];
    float a0 = 0.f, a1 = 0.f, a2 = 0.f;
    #pragma unroll
    for (int j = 0; j < 31; ++j) {
      const int c = q * 31 + j;
      const float4 wv = w4[j];
      const float4 y0 = va[c];
      a0 = fmaf(wv.x, y0.x, fmaf(wv.y, y0.y, fmaf(wv.z, y0.z, fmaf(wv.w, y0.w, a0))));
    }
    if (nk > 1) {
      #pragma unroll
      for (int j = 0; j < 31; ++j) {
        const int c = q * 31 + j;
        const float4 wv = w4[j];
        const float4 y1 = vb[c];
        a1 = fmaf(wv.x, y1.x, fmaf(wv.y, y1.y, fmaf(wv.z, y1.z, fmaf(wv.w, y1.w, a1))));
      }
    }
    if (nk > 2) {
      #pragma unroll
      for (int j = 0; j < 31; ++j) {
        const int c = q * 31 + j;
        const float4 wv = w4[j];
        const float4 y2 = vc[c];
        a2 = fmaf(wv.x, y2.x, fmaf(wv.y, y2.y, fmaf(wv.z, y2.z, fmaf(wv.w, y2.w, a2))));
      }
    }
    part[0][tid] = a0; part[1][tid] = a1; part[2][tid] = a2;
    __syncthreads();

    // ---- cell + publish (wave 0)
    if (tid < 48) {
      const int k = tid >> 4, uu = tid & 15;
      const int f = f_lo + k;
      const bool act = (f <= f_hi);
      float hn = 0.f;
      int t = 0;
      if (act) {
        t = m - 6 * f;
        const int b3 = f % 3;
        float gg[4];
        #pragma unroll
        for (int g2 = 0; g2 < 4; ++g2) {
          const int rr = 4 * uu + g2;
          float s = part[k][rr] + part[k][rr + 64] + part[k][rr + 128] +
                    part[k][rr + 192] + bias[rr];
          if (l == 0 && f == 0) {          // f==0: x is the raw 12-dim seed
            #pragma unroll
            for (int c = 0; c < CDIM; ++c) s = fmaf(wih0s[rr][c], xs[t][c], s);
          }
          gg[g2] = s;
        }
        if (uu < U) {
          const float cp = (t == 0) ? 0.f : cst[b3][uu];
          const float cn = sigf(gg[1]) * cp + sigf(gg[0]) * tanhf(gg[2]);
          hn = sigf(gg[3]) * tanhf(cn);
          cst[b3][uu] = cn;
        }
      }
      const float hi = __shfl(hn, tid | 1);   // pair-pack (hn=0 beyond U)
      if (act && (uu & 1) == 0 && uu < U) {
        const u64 pv = ((u64)__float_as_uint(hi) << 32) | (u64)__float_as_uint(hn);
        __hip_atomic_store(hu + ((size_t)l * NSLOT + 16 * f + t) * hps + (j0 >> 1) + (uu >> 1),
                           pv, __ATOMIC_RELAXED, AG);
      }
    }
    // all wave-0 data stores ACKed at the coherence point, THEN count up
    asm volatile("s_waitcnt vmcnt(0)" ::: "memory");
    if (tid < 48 && (tid & 15) == 0) {
      const int k = tid >> 4, f = f_lo + k;
      if (f <= f_hi)   // slot = 16f + (m-6f) = 10f + m
        __hip_atomic_fetch_add(cnt + l * NSLOT + 10 * f + m, 1, __ATOMIC_RELAXED, AG);
    }
    // 2 barriers/tick; publish completes before next tick's stage barrier.
  }
}

extern "C" void kernel_launch(void* const* d_in, const int* in_sizes, int n_in,
                              void* d_out, int out_size, void* d_ws, size_t ws_size,
                              hipStream_t stream) {
  const float* X    = (const float*)d_in[0];
  const float* Wih0 = (const float*)d_in[1];
  const float* Wih  = (const float*)d_in[2];
  const float* Whh  = (const float*)d_in[3];
  const float* bih  = (const float*)d_in[4];
  const float* bhh  = (const float*)d_in[5];
  const float* Wl   = (const float*)d_in[6];
  const float* bl   = (const float*)d_in[7];

  // workspace: hout[6][1536][hp] f32 + cnt[6][1536] i32
  size_t need240 = (size_t)NL * NSLOT * 240 * 4 + (size_t)NL * NSLOT * 4;
  const int hp = (ws_size >= need240) ? 240 : 234;
  float* hout = (float*)d_ws;
  int* cnt = (int*)(hout + (size_t)NL * NSLOT * hp);

  init_kernel<<<2048, 256, 0, stream>>>((unsigned*)hout, cnt, hp);
  lstm_pipe<<<NL * GPL + NHEAD, BLOCK, 0, stream>>>(
      X, Wih0, Wih, Whh, bih, bhh, Wl, bl, (float*)d_out, hout, cnt, hp / 2);
}